// Round 6
// baseline (311.068 us; speedup 1.0000x reference)
//
#include <hip/hip_runtime.h>
#include <stdint.h>

typedef __attribute__((ext_vector_type(8))) unsigned short ushort8;
typedef __attribute__((ext_vector_type(8))) __bf16 bf16x8;
typedef __attribute__((ext_vector_type(4))) float f32x4;
typedef __attribute__((ext_vector_type(4))) uint32_t u32x4;

__device__ __forceinline__ unsigned short f2bf(float f) {
  union { float f; uint32_t u; } x; x.f = f;
  uint32_t u = x.u;
  uint32_t r = (u + 0x7fffu + ((u >> 16) & 1u)) >> 16;
  return (unsigned short)r;
}

__device__ __forceinline__ uint32_t pack_bf2(float lo, float hi) {
  return (uint32_t)f2bf(lo) | ((uint32_t)f2bf(hi) << 16);
}

// round-half-up bf16 pair pack: 2 adds + 1 v_perm (≡ RNE for positive non-ties)
__device__ __forceinline__ uint32_t rhu2(float lo, float hi) {
  union { float f; uint32_t u; } a, b; a.f = lo; b.f = hi;
  return __builtin_amdgcn_perm(b.u + 0x8000u, a.u + 0x8000u, 0x07060302u);
}

__device__ __forceinline__ void store_c(unsigned short* p, float v) { *p = f2bf(v); }
__device__ __forceinline__ void store_c(float* p, float v) { *p = v; }

__device__ __forceinline__ void gll16(const unsigned short* g, unsigned short* l) {
  __builtin_amdgcn_global_load_lds((const __attribute__((address_space(1))) void*)g,
                                   (__attribute__((address_space(3))) void*)l,
                                   16, 0, 0);
}

// ---------------------------------------------------------------------------
// fp32 -> bf16 convert (RNE). One thread = 4 elements.
// ---------------------------------------------------------------------------
__global__ __launch_bounds__(256) void cvt_f32_bf16(
    const float* __restrict__ x, unsigned short* __restrict__ y, int n4) {
  int i = blockIdx.x * 256 + threadIdx.x;
  if (i >= n4) return;
  float4 v = *(const float4*)(x + (size_t)i * 4);
  uint2 p; p.x = pack_bf2(v.x, v.y); p.y = pack_bf2(v.z, v.w);
  *(uint2*)(y + (size_t)i * 4) = p;
}

// ---------------------------------------------------------------------------
// Weight transpose + convert: WT[n][k] = bf16(W[k][n]), 1024x1024 fp32 in.
// ---------------------------------------------------------------------------
__device__ __forceinline__ void transpose_body(const float* W, unsigned short* WT) {
  __shared__ unsigned short tile[32][33];
  int c0 = blockIdx.x * 32, r0 = blockIdx.y * 32;
  int x = threadIdx.x, y = threadIdx.y;
#pragma unroll
  for (int i = 0; i < 32; i += 8)
    tile[y + i][x] = f2bf(W[(size_t)(r0 + y + i) * 1024 + c0 + x]);
  __syncthreads();
#pragma unroll
  for (int i = 0; i < 32; i += 8)
    WT[(size_t)(c0 + y + i) * 1024 + r0 + x] = tile[x][y + i];
}

__global__ void transpose_w(const float* __restrict__ W,
                            unsigned short* __restrict__ WT) {
  transpose_body(W, WT);
}

__global__ void transpose_w3(const float* W0, const float* W1, const float* W2,
                             unsigned short* T0, unsigned short* T1,
                             unsigned short* T2) {
  const float* W = (blockIdx.z == 0) ? W0 : (blockIdx.z == 1) ? W1 : W2;
  unsigned short* WT = (blockIdx.z == 0) ? T0 : (blockIdx.z == 1) ? T1 : T2;
  transpose_body(W, WT);
}

// ---------------------------------------------------------------------------
// GEMM R15 (gemm5): C[M,N] = A[M,K]*B[K,N] given BT[N,K], bf16, fp32 accum.
// Counted-vmcnt triple-buffered template (T3+T4 proper, not a graft):
//   BM=256, BN=128, BK=64; 512 thr = 8 waves (4m x 2n), per-wave 64x64 out.
//   LDS: 3 slots x (A 32K + B 16K) = 144 KB -> 1 block/CU, 8 waves.
// Stage stream: tile = 6 gll16/wave (A parts 0-3, B parts 4-5; each part =
// 64 rows x 128 B, one gll16 per wave covering its 8 rows). Stream order:
//   prologue: t0 p0..5, t1 p0..3              (10 loads/wave)
//   tile-t window: (t+1,p4)(t+1,p5)(t+2,p0)  | (t+2,p1)(t+2,p2)(t+2,p3)
// => at tile-t start exactly the newest 4 loads (t+1's A-parts) may be in
// flight: s_waitcnt vmcnt(4) + s_barrier, NEVER vmcnt(0) except last tile.
// Slot safety by barriers (not timing): tile t+2 -> slot (t+2)%3 = slot of
// tile t-1, whose ds_reads were consumed by MFMAs (compiler lgkm waits)
// before each wave entered the tile-t start barrier; stages issue after it.
// Per tile, 2 phases {stage 3 | 8 ds_read_b128 | setprio + 16 MFMA}, one
// mid-tile cohesion barrier (no drain). Both-sides XOR swizzle as verified:
// 16B chunk j of row r holds global chunk j^(r&7); source pre-swizzled
// (lane-constant since row&7 == (tid>>3)&7), reads XOR by fr&7.
// Grid: QKV (8,32,3)=768 = 3 exact CU-rounds; final (8,32,1)=256 = 1 round.
// sc0: epilogue scale when z==0 (folds attn head_scale*log2e into q proj).
// ---------------------------------------------------------------------------
template <typename OutT>
__global__ __launch_bounds__(512, 2) void gemm5(
    const unsigned short* A,
    const unsigned short* BT0, const unsigned short* BT1, const unsigned short* BT2,
    OutT* C0, OutT* C1, OutT* C2,
    int M, int N, int K, float sc0) {
  const int z = blockIdx.z;
  const unsigned short* BT = (z == 0) ? BT0 : (z == 1) ? BT1 : BT2;
  OutT* C = (z == 0) ? C0 : (z == 1) ? C1 : C2;
  const float sc = (z == 0) ? sc0 : 1.0f;

  __shared__ __attribute__((aligned(16))) unsigned short As[3 * 256 * 64];
  __shared__ __attribute__((aligned(16))) unsigned short Bs[3 * 128 * 64];

  const int tid = threadIdx.x;
  const int wave = tid >> 6, lane = tid & 63;
  const int fr = lane & 15, fq = lane >> 4;
  const int wm = wave >> 1, wn = wave & 1;
  const int bm = blockIdx.y * 256, bn = blockIdx.x * 128;

  // staging source: lane covers (row = 8*wave + (lane>>3) within part,
  // chunk = lane&7), source chunk pre-swizzled by row&7 = (tid>>3)&7.
  const int r8 = tid >> 3, c8 = tid & 7;
  const int s8 = (c8 ^ (r8 & 7)) * 8;
  const unsigned short* Ag = A + (size_t)(bm + r8) * K + s8;
  const unsigned short* Bg = BT + (size_t)(bn + r8) * K + s8;

  const int NT = K >> 6;  // 16

  // one staging load: tile's part (0-3 = A 64-row block, 4-5 = B 64-row blk)
  auto stage = [&](int tile, int part) {
    if (tile >= NT) return;
    const int slot = tile % 3;
    const size_t k0 = (size_t)tile * 64;
    if (part < 4) {
      gll16(Ag + k0 + (size_t)(part * 64) * K,
            &As[slot * (256 * 64) + (part * 64 + 8 * wave) * 64]);
    } else {
      const int p = part - 4;
      gll16(Bg + k0 + (size_t)(p * 64) * K,
            &Bs[slot * (128 * 64) + (p * 64 + 8 * wave) * 64]);
    }
  };

  f32x4 acc[4][4] = {};

  // prologue: 10 loads/wave = tile0 complete + tile1 A-parts
  stage(0, 0); stage(0, 1); stage(0, 2); stage(0, 3); stage(0, 4); stage(0, 5);
  stage(1, 0); stage(1, 1); stage(1, 2); stage(1, 3);

  for (int t = 0; t < NT; ++t) {
    if (t + 1 < NT)
      asm volatile("s_waitcnt vmcnt(4)" ::: "memory");
    else
      asm volatile("s_waitcnt vmcnt(0)" ::: "memory");
    __builtin_amdgcn_s_barrier();        // slot t%3 fully landed for ALL waves
    __builtin_amdgcn_sched_barrier(0);

    const unsigned short* Asl = &As[(t % 3) * (256 * 64)];
    const unsigned short* Bsl = &Bs[(t % 3) * (128 * 64)];

#pragma unroll
    for (int kh = 0; kh < 2; ++kh) {
      // stage stream for this phase (targets tiles t+1 / t+2, other slots)
      if (kh == 0) {
        stage(t + 1, 4); stage(t + 1, 5); stage(t + 2, 0);
      } else {
        stage(t + 2, 1); stage(t + 2, 2); stage(t + 2, 3);
      }

      bf16x8 af[4], bfr[4];
#pragma unroll
      for (int mt = 0; mt < 4; mt++)
        af[mt] = *(const bf16x8*)&Asl[(wm * 64 + mt * 16 + fr) * 64 +
                                      (((kh * 4 + fq) ^ (fr & 7)) * 8)];
#pragma unroll
      for (int nt = 0; nt < 4; nt++)
        bfr[nt] = *(const bf16x8*)&Bsl[(wn * 64 + nt * 16 + fr) * 64 +
                                       (((kh * 4 + fq) ^ (fr & 7)) * 8)];

      __builtin_amdgcn_s_setprio(1);
#pragma unroll
      for (int mt = 0; mt < 4; mt++)
#pragma unroll
        for (int nt = 0; nt < 4; nt++)
          acc[mt][nt] = __builtin_amdgcn_mfma_f32_16x16x32_bf16(
              af[mt], bfr[nt], acc[mt][nt], 0, 0, 0);
      __builtin_amdgcn_s_setprio(0);

      if (kh == 0) __builtin_amdgcn_s_barrier();  // mid-tile cohesion, no drain
    }
  }

#pragma unroll
  for (int mt = 0; mt < 4; mt++)
#pragma unroll
    for (int nt = 0; nt < 4; nt++)
#pragma unroll
      for (int r = 0; r < 4; r++) {
        int row = bm + wm * 64 + mt * 16 + fq * 4 + r;
        int col = bn + wn * 64 + nt * 16 + fr;
        store_c(&C[(size_t)row * N + col], acc[mt][nt][r] * sc);
      }
}

// ---------------------------------------------------------------------------
// Flash attention R11 (unchanged, verified): XOR-swizzled zero-conflict LDS,
// K double-buffered via global_load_lds prefetch issued after barrier B,
// V staged single-buffered with short reg live range, q pre-scaled,
// setprio on MFMA clusters.
// ---------------------------------------------------------------------------
__global__ __launch_bounds__(256, 4) void attn_kernel(
    const unsigned short* q, const unsigned short* k,
    const unsigned short* v, unsigned short* o) {
  const int S = 2048, E = 1024;
  __shared__ __attribute__((aligned(16))) unsigned short Ksb[2 * 64 * 64];
  __shared__ __attribute__((aligned(16))) unsigned short Vtb[64 * 64];

  const int tid = threadIdx.x;
  const int wave = tid >> 6, lane = tid & 63;
  const int fr = lane & 15, fq = lane >> 4;
  const int q0 = blockIdx.x * 128;
  const int bh = blockIdx.y;
  const int b = bh >> 4, h = bh & 15;
  const size_t base = ((size_t)b * S) * E + (size_t)h * 64;

  bf16x8 aq[2][2];
#pragma unroll
  for (int qg = 0; qg < 2; qg++)
#pragma unroll
    for (int ks = 0; ks < 2; ks++)
      aq[qg][ks] = *(const bf16x8*)&q[base +
          (size_t)(q0 + qg * 64 + wave * 16 + fr) * E + ks * 32 + fq * 8];

  ushort8 ones_u;
#pragma unroll
  for (int j = 0; j < 8; j++) ones_u[j] = 0x3F80;  // bf16 1.0
  bf16x8 onesf = *(bf16x8*)&ones_u;

  f32x4 ot[2][4] = {};
  f32x4 osum[2] = {};

  const int srow = lane >> 3;
  const int scol = (((lane & 7) ^ srow) << 3);
  const unsigned short* Kg = k + base + (size_t)(wave * 16 + srow) * E + scol;

  const int rp = (tid & 31) * 2;
  const int dcv = (tid >> 5) * 8;
  const int u_ = rp & 31;
  const int slot = 32 * (rp >> 5) + 8 * ((u_ & 15) >> 2) + 4 * (u_ >> 4) + (u_ & 3);
  const unsigned short* Vg = v + base + (size_t)rp * E + dcv;

  const int rx = (fr & 7) << 3;

  gll16(Kg, &Ksb[wave * 1024]);
  gll16(Kg + 8 * (size_t)E, &Ksb[wave * 1024 + 512]);

  int cur = 0;
  for (int t = 0; t < 32; t++) {
    const int nxt = cur ^ 4096;

    const size_t toff = (size_t)t * 64 * E;
    u32x4 va = *(const u32x4*)(Vg + toff);
    u32x4 vb = *(const u32x4*)(Vg + toff + E);

    __syncthreads();  // A: drains K[t] (prefetched a phase ago) + va/vb

#pragma unroll
    for (int w = 0; w < 4; w++) {
      uint32_t lo = __builtin_amdgcn_perm(vb[w], va[w], 0x05040100u);
      uint32_t hi = __builtin_amdgcn_perm(vb[w], va[w], 0x07060302u);
      int d = dcv + 2 * w;
      *(uint32_t*)&Vtb[d * 64 + (slot ^ ((2 * w) << 3))] = lo;
      *(uint32_t*)&Vtb[(d + 1) * 64 + (slot ^ ((2 * w + 1) << 3))] = hi;
    }

    __syncthreads();  // B: staged data visible

    if (t < 31) {
      const size_t poff = (size_t)(t + 1) * 64 * E;
      gll16(Kg + poff, &Ksb[nxt + wave * 1024]);
      gll16(Kg + poff + 8 * (size_t)E, &Ksb[nxt + wave * 1024 + 512]);
    }

    f32x4 st[2][4] = {};
    __builtin_amdgcn_s_setprio(1);
#pragma unroll
    for (int ks = 0; ks < 2; ks++) {
#pragma unroll
      for (int tt = 0; tt < 4; tt++) {
        bf16x8 ak = *(const bf16x8*)&Ksb[cur + (tt * 16 + fr) * 64 +
                                         ((ks * 32 + fq * 8) ^ rx)];
        st[0][tt] = __builtin_amdgcn_mfma_f32_16x16x32_bf16(ak, aq[0][ks], st[0][tt], 0, 0, 0);
        st[1][tt] = __builtin_amdgcn_mfma_f32_16x16x32_bf16(ak, aq[1][ks], st[1][tt], 0, 0, 0);
      }
    }
    __builtin_amdgcn_s_setprio(0);

    uint32_t pk[2][4][2];
#pragma unroll
    for (int qg = 0; qg < 2; qg++)
#pragma unroll
      for (int tt = 0; tt < 4; tt++) {
        float e0 = __builtin_amdgcn_exp2f(st[qg][tt][0]);
        float e1 = __builtin_amdgcn_exp2f(st[qg][tt][1]);
        float e2 = __builtin_amdgcn_exp2f(st[qg][tt][2]);
        float e3 = __builtin_amdgcn_exp2f(st[qg][tt][3]);
        pk[qg][tt][0] = rhu2(e0, e1);
        pk[qg][tt][1] = rhu2(e2, e3);
      }

    __builtin_amdgcn_s_setprio(1);
#pragma unroll
    for (int c = 0; c < 2; c++) {
      bf16x8 bp[2];
#pragma unroll
      for (int qg = 0; qg < 2; qg++) {
        u32x4 bpr;
        bpr[0] = pk[qg][2 * c][0];
        bpr[1] = pk[qg][2 * c][1];
        bpr[2] = pk[qg][2 * c + 1][0];
        bpr[3] = pk[qg][2 * c + 1][1];
        bp[qg] = *(bf16x8*)&bpr;
      }
#pragma unroll
      for (int dt = 0; dt < 4; dt++) {
        bf16x8 av = *(const bf16x8*)&Vtb[(dt * 16 + fr) * 64 +
                                         ((c * 32 + fq * 8) ^ rx)];
        ot[0][dt] = __builtin_amdgcn_mfma_f32_16x16x32_bf16(av, bp[0], ot[0][dt], 0, 0, 0);
        ot[1][dt] = __builtin_amdgcn_mfma_f32_16x16x32_bf16(av, bp[1], ot[1][dt], 0, 0, 0);
      }
      osum[0] = __builtin_amdgcn_mfma_f32_16x16x32_bf16(onesf, bp[0], osum[0], 0, 0, 0);
      osum[1] = __builtin_amdgcn_mfma_f32_16x16x32_bf16(onesf, bp[1], osum[1], 0, 0, 0);
    }
    __builtin_amdgcn_s_setprio(0);

    cur = nxt;
  }

#pragma unroll
  for (int qg = 0; qg < 2; qg++) {
    float inv = 1.0f / osum[qg][0];
    size_t rowbase = base + (size_t)(q0 + qg * 64 + wave * 16 + fr) * E;
#pragma unroll
    for (int dt = 0; dt < 4; dt++) {
      uint32_t w0 = rhu2(ot[qg][dt][0] * inv, ot[qg][dt][1] * inv);
      uint32_t w1 = rhu2(ot[qg][dt][2] * inv, ot[qg][dt][3] * inv);
      *(uint32_t*)&o[rowbase + dt * 16 + fq * 4] = w0;
      *(uint32_t*)&o[rowbase + dt * 16 + fq * 4 + 2] = w1;
    }
  }
}

// ---------------------------------------------------------------------------
// ws: 3 x 1M (weights) + 3 x 8M (q/k/v) shorts = 54 MB.
// bf16 hidden_states lives in d_out's first 16 MB (dead before final GEMM).
// woT reuses wqT's slot (transposed only after the QKV GEMM has consumed
// wqT). Final GEMM writes fp32 to d_out.
// ---------------------------------------------------------------------------
extern "C" void kernel_launch(void* const* d_in, const int* in_sizes, int n_in,
                              void* d_out, int out_size, void* d_ws, size_t ws_size,
                              hipStream_t stream) {
  const float* hs = (const float*)d_in[0];
  const float* wq = (const float*)d_in[1];
  const float* wk = (const float*)d_in[2];
  const float* wv = (const float*)d_in[3];
  const float* wo = (const float*)d_in[4];
  unsigned short* ws = (unsigned short*)d_ws;

  unsigned short* wqT = ws;
  unsigned short* wkT = ws + 1048576;
  unsigned short* wvT = ws + 2097152;
  unsigned short* woT = wqT;
  unsigned short* qb  = ws + 3145728;
  unsigned short* kb  = qb + 8388608;
  unsigned short* vb  = kb + 8388608;
  unsigned short* ob  = qb;
  unsigned short* hsb = (unsigned short*)d_out;
  float* out = (float*)d_out;

  const int M = 8192, N = 1024, K = 1024;
  const float KSC = 0.125f * 1.44269504088896341f;  // head_scale * log2(e)

  cvt_f32_bf16<<<dim3(M * K / 4 / 256), 256, 0, stream>>>(hs, hsb, M * K / 4);

  dim3 tb(32, 8);
  transpose_w3<<<dim3(32, 32, 3), tb, 0, stream>>>(wq, wk, wv, wqT, wkT, wvT);

  // grid (bn=8, bm=32, z=3) = 768 blocks = 3 exact rounds at 1 block/CU
  gemm5<unsigned short><<<dim3(8, 32, 3), 512, 0, stream>>>(
      hsb, wqT, wkT, wvT, qb, kb, vb, M, N, K, KSC);

  transpose_w<<<dim3(32, 32), tb, 0, stream>>>(wo, woT);

  attn_kernel<<<dim3(2048 / 128, 64), 256, 0, stream>>>(qb, kb, vb, ob);

  // grid (8, 32, 1) = 256 blocks = 1 exact round
  gemm5<float><<<dim3(8, 32, 1), 512, 0, stream>>>(
      ob, woT, woT, woT, out, out, out, M, N, K, 1.0f);
}

// Round 7
// 260.943 us; speedup vs baseline: 1.1921x; 1.1921x over previous
//
#include <hip/hip_runtime.h>
#include <stdint.h>

typedef __attribute__((ext_vector_type(8))) unsigned short ushort8;
typedef __attribute__((ext_vector_type(8))) __bf16 bf16x8;
typedef __attribute__((ext_vector_type(4))) float f32x4;
typedef __attribute__((ext_vector_type(4))) uint32_t u32x4;

__device__ __forceinline__ unsigned short f2bf(float f) {
  union { float f; uint32_t u; } x; x.f = f;
  uint32_t u = x.u;
  uint32_t r = (u + 0x7fffu + ((u >> 16) & 1u)) >> 16;
  return (unsigned short)r;
}

__device__ __forceinline__ uint32_t pack_bf2(float lo, float hi) {
  return (uint32_t)f2bf(lo) | ((uint32_t)f2bf(hi) << 16);
}

// round-half-up bf16 pair pack: 2 adds + 1 v_perm (≡ RNE for positive non-ties)
__device__ __forceinline__ uint32_t rhu2(float lo, float hi) {
  union { float f; uint32_t u; } a, b; a.f = lo; b.f = hi;
  return __builtin_amdgcn_perm(b.u + 0x8000u, a.u + 0x8000u, 0x07060302u);
}

__device__ __forceinline__ void store_c(unsigned short* p, float v) { *p = f2bf(v); }
__device__ __forceinline__ void store_c(float* p, float v) { *p = v; }

__device__ __forceinline__ void gll16(const unsigned short* g, unsigned short* l) {
  __builtin_amdgcn_global_load_lds((const __attribute__((address_space(1))) void*)g,
                                   (__attribute__((address_space(3))) void*)l,
                                   16, 0, 0);
}

// ---------------------------------------------------------------------------
// fp32 -> bf16 convert (RNE). One thread = 4 elements.
// ---------------------------------------------------------------------------
__global__ __launch_bounds__(256) void cvt_f32_bf16(
    const float* __restrict__ x, unsigned short* __restrict__ y, int n4) {
  int i = blockIdx.x * 256 + threadIdx.x;
  if (i >= n4) return;
  float4 v = *(const float4*)(x + (size_t)i * 4);
  uint2 p; p.x = pack_bf2(v.x, v.y); p.y = pack_bf2(v.z, v.w);
  *(uint2*)(y + (size_t)i * 4) = p;
}

// ---------------------------------------------------------------------------
// Weight transpose + convert: WT[n][k] = bf16(W[k][n]), 1024x1024 fp32 in.
// Batched x3 (wq/wk/wv) via blockIdx.z; single version kept for wo.
// ---------------------------------------------------------------------------
__device__ __forceinline__ void transpose_body(const float* W, unsigned short* WT) {
  __shared__ unsigned short tile[32][33];
  int c0 = blockIdx.x * 32, r0 = blockIdx.y * 32;
  int x = threadIdx.x, y = threadIdx.y;
#pragma unroll
  for (int i = 0; i < 32; i += 8)
    tile[y + i][x] = f2bf(W[(size_t)(r0 + y + i) * 1024 + c0 + x]);
  __syncthreads();
#pragma unroll
  for (int i = 0; i < 32; i += 8)
    WT[(size_t)(c0 + y + i) * 1024 + r0 + x] = tile[x][y + i];
}

__global__ void transpose_w(const float* __restrict__ W,
                            unsigned short* __restrict__ WT) {
  transpose_body(W, WT);
}

__global__ void transpose_w3(const float* W0, const float* W1, const float* W2,
                             unsigned short* T0, unsigned short* T1,
                             unsigned short* T2) {
  const float* W = (blockIdx.z == 0) ? W0 : (blockIdx.z == 1) ? W1 : W2;
  unsigned short* WT = (blockIdx.z == 0) ? T0 : (blockIdx.z == 1) ? T1 : T2;
  transpose_body(W, WT);
}

// ---------------------------------------------------------------------------
// GEMM (gemm3, R13 verified-best): C[M,N] = A[M,K]*B[K,N] given BT[N,K].
// 128x128 tile, BK=64, 256 thr (4 waves as 2m x 2n, each 64x64 out).
// Double-buffered LDS = 64 KB -> 2 blocks/CU (TLP beats pipeline depth here:
// R12 1-block/CU 96KB and R15 1-block/CU 144KB both regressed).
// ONE barrier per K-step:
//   prologue: STAGE(t0 -> buf0)
//   loop t:   __syncthreads()      // drains STAGE(t), in flight one phase
//             STAGE(t+1 -> buf^1)  // after barrier -> not drained by it
//             ds_read buf[cur], 32 MFMA per wave
// Both-sides XOR swizzle (verified R11-R13): 16B chunk j of row r holds
// global chunk j^(r&7); gll16 dest linear, source column pre-swizzled
// (lane-constant: row&7 == (tid>>3)&7 for every staged line), reads XOR.
// sc0: epilogue scale when blockIdx.z == 0 (folds attn head_scale*log2e
// into the q projection; 1.0f elsewhere).
// ---------------------------------------------------------------------------
template <typename OutT>
__global__ __launch_bounds__(256, 2) void gemm3(
    const unsigned short* A,
    const unsigned short* BT0, const unsigned short* BT1, const unsigned short* BT2,
    OutT* C0, OutT* C1, OutT* C2,
    int M, int N, int K, float sc0) {
  const unsigned short* BT = (blockIdx.z == 0) ? BT0 : (blockIdx.z == 1) ? BT1 : BT2;
  OutT* C = (blockIdx.z == 0) ? C0 : (blockIdx.z == 1) ? C1 : C2;
  const float sc = (blockIdx.z == 0) ? sc0 : 1.0f;

  __shared__ __attribute__((aligned(16))) unsigned short As[2][128 * 64];
  __shared__ __attribute__((aligned(16))) unsigned short Bs[2][128 * 64];

  const int tid = threadIdx.x;
  const int wave = tid >> 6, lane = tid & 63;
  const int fr = lane & 15, fq = lane >> 4;
  const int wm = wave >> 1, wn = wave & 1;
  const int bm = blockIdx.x * 128, bn = blockIdx.y * 128;

  const int r8 = tid >> 3, c8 = tid & 7;
  const int s8 = c8 ^ (r8 & 7);
  const unsigned short* Ag = A + (size_t)(bm + r8) * K + s8 * 8;
  const unsigned short* Bg = BT + (size_t)(bn + r8) * K + s8 * 8;

  f32x4 acc[4][4] = {};
  const int rx = fr & 7;  // read-side swizzle (16B-chunk units)

  const int NT = K >> 6;

#pragma unroll
  for (int i = 0; i < 4; i++) {
    gll16(Ag + (size_t)(i * 32) * K, &As[0][(i * 32 + wave * 8) * 64]);
    gll16(Bg + (size_t)(i * 32) * K, &Bs[0][(i * 32 + wave * 8) * 64]);
  }

  int cur = 0;
  for (int t = 0; t < NT; ++t) {
    __syncthreads();  // drains STAGE(t) (in flight one full compute phase)

    if (t + 1 < NT) {
      const int b = cur ^ 1;
      const size_t k0 = (size_t)(t + 1) * 64;
#pragma unroll
      for (int i = 0; i < 4; i++) {
        gll16(Ag + k0 + (size_t)(i * 32) * K, &As[b][(i * 32 + wave * 8) * 64]);
        gll16(Bg + k0 + (size_t)(i * 32) * K, &Bs[b][(i * 32 + wave * 8) * 64]);
      }
    }

#pragma unroll
    for (int kh = 0; kh < 2; ++kh) {
      bf16x8 af[4], bfr[4];
#pragma unroll
      for (int mt = 0; mt < 4; mt++)
        af[mt] = *(const bf16x8*)&As[cur][(wm * 64 + mt * 16 + fr) * 64 +
                                          (((kh * 4 + fq) ^ rx) * 8)];
#pragma unroll
      for (int nt = 0; nt < 4; nt++)
        bfr[nt] = *(const bf16x8*)&Bs[cur][(wn * 64 + nt * 16 + fr) * 64 +
                                           (((kh * 4 + fq) ^ rx) * 8)];
#pragma unroll
      for (int mt = 0; mt < 4; mt++)
#pragma unroll
        for (int nt = 0; nt < 4; nt++)
          acc[mt][nt] = __builtin_amdgcn_mfma_f32_16x16x32_bf16(af[mt], bfr[nt], acc[mt][nt], 0, 0, 0);
    }
    cur ^= 1;
  }

#pragma unroll
  for (int mt = 0; mt < 4; mt++)
#pragma unroll
    for (int nt = 0; nt < 4; nt++)
#pragma unroll
      for (int r = 0; r < 4; r++) {
        int row = bm + wm * 64 + mt * 16 + fq * 4 + r;
        int col = bn + wn * 64 + nt * 16 + fr;
        store_c(&C[(size_t)row * N + col], acc[mt][nt][r] * sc);
      }
}

// ---------------------------------------------------------------------------
// Flash attention R16: R11 + T14 async-STAGE for V and phase reorder.
// Per iter:  barrier A (drains K[t]+V[t], both issued a full phase ago ->
//            free)  ->  Vt ds_writes (from regs) overlapped with S^T (reads
//            Ksb only)  ->  barrier B (Vt visible; ZERO vmem outstanding ->
//            free)  ->  issue K[t+1] gll16 + V[t+1] global loads  ->  exp2 +
//            pack  ->  PV (reads Vtb).
// Races: Vtb overwritten only after barrier A, which retires prev PV's
// ds_reads; Ksb[nxt] written by gll16 issued after barrier B, read after
// next barrier A (drained). va/vb live across exp2+PV (8 VGPR).
// ---------------------------------------------------------------------------
__global__ __launch_bounds__(256, 4) void attn_kernel(
    const unsigned short* q, const unsigned short* k,
    const unsigned short* v, unsigned short* o) {
  const int S = 2048, E = 1024;
  __shared__ __attribute__((aligned(16))) unsigned short Ksb[2 * 64 * 64];
  __shared__ __attribute__((aligned(16))) unsigned short Vtb[64 * 64];

  const int tid = threadIdx.x;
  const int wave = tid >> 6, lane = tid & 63;
  const int fr = lane & 15, fq = lane >> 4;
  const int q0 = blockIdx.x * 128;
  const int bh = blockIdx.y;
  const int b = bh >> 4, h = bh & 15;
  const size_t base = ((size_t)b * S) * E + (size_t)h * 64;

  bf16x8 aq[2][2];
#pragma unroll
  for (int qg = 0; qg < 2; qg++)
#pragma unroll
    for (int ks = 0; ks < 2; ks++)
      aq[qg][ks] = *(const bf16x8*)&q[base +
          (size_t)(q0 + qg * 64 + wave * 16 + fr) * E + ks * 32 + fq * 8];

  ushort8 ones_u;
#pragma unroll
  for (int j = 0; j < 8; j++) ones_u[j] = 0x3F80;  // bf16 1.0
  bf16x8 onesf = *(bf16x8*)&ones_u;

  f32x4 ot[2][4] = {};
  f32x4 osum[2] = {};

  const int srow = lane >> 3;
  const int scol = (((lane & 7) ^ srow) << 3);
  const unsigned short* Kg = k + base + (size_t)(wave * 16 + srow) * E + scol;

  const int rp = (tid & 31) * 2;
  const int dcv = (tid >> 5) * 8;
  const int u_ = rp & 31;
  const int slot = 32 * (rp >> 5) + 8 * ((u_ & 15) >> 2) + 4 * (u_ >> 4) + (u_ & 3);
  const unsigned short* Vg = v + base + (size_t)rp * E + dcv;

  const int rx = (fr & 7) << 3;

  // prologue: K chunk 0 -> LDS (in flight), V chunk 0 -> regs (in flight)
  gll16(Kg, &Ksb[wave * 1024]);
  gll16(Kg + 8 * (size_t)E, &Ksb[wave * 1024 + 512]);
  u32x4 va = *(const u32x4*)(Vg);
  u32x4 vb = *(const u32x4*)(Vg + E);

  int cur = 0;
  for (int t = 0; t < 32; t++) {
    const int nxt = cur ^ 4096;

    __syncthreads();  // A: drains K[t] + va/vb — all issued a full phase ago

    // stage Vt from regs; overlaps with S^T below (different consumers)
#pragma unroll
    for (int w = 0; w < 4; w++) {
      uint32_t lo = __builtin_amdgcn_perm(vb[w], va[w], 0x05040100u);
      uint32_t hi = __builtin_amdgcn_perm(vb[w], va[w], 0x07060302u);
      int d = dcv + 2 * w;
      *(uint32_t*)&Vtb[d * 64 + (slot ^ ((2 * w) << 3))] = lo;
      *(uint32_t*)&Vtb[(d + 1) * 64 + (slot ^ ((2 * w + 1) << 3))] = hi;
    }

    // S^T: reads Ksb[cur] only (visible since barrier A)
    f32x4 st[2][4] = {};
    __builtin_amdgcn_s_setprio(1);
#pragma unroll
    for (int ks = 0; ks < 2; ks++) {
#pragma unroll
      for (int tt = 0; tt < 4; tt++) {
        bf16x8 ak = *(const bf16x8*)&Ksb[cur + (tt * 16 + fr) * 64 +
                                         ((ks * 32 + fq * 8) ^ rx)];
        st[0][tt] = __builtin_amdgcn_mfma_f32_16x16x32_bf16(ak, aq[0][ks], st[0][tt], 0, 0, 0);
        st[1][tt] = __builtin_amdgcn_mfma_f32_16x16x32_bf16(ak, aq[1][ks], st[1][tt], 0, 0, 0);
      }
    }
    __builtin_amdgcn_s_setprio(0);

    __syncthreads();  // B: Vt visible; no vmem outstanding -> free drain

    // prefetch chunk t+1: K -> LDS[nxt] (zero reg cost), V -> regs (8 VGPR,
    // live across exp2+PV; drained for free at next barrier A)
    if (t < 31) {
      const size_t poff = (size_t)(t + 1) * 64 * E;
      gll16(Kg + poff, &Ksb[nxt + wave * 1024]);
      gll16(Kg + poff + 8 * (size_t)E, &Ksb[nxt + wave * 1024 + 512]);
      va = *(const u32x4*)(Vg + poff);
      vb = *(const u32x4*)(Vg + poff + E);
    }

    // exp2 (scale pre-folded into q) + round-half-up pair pack
    uint32_t pk[2][4][2];
#pragma unroll
    for (int qg = 0; qg < 2; qg++)
#pragma unroll
      for (int tt = 0; tt < 4; tt++) {
        float e0 = __builtin_amdgcn_exp2f(st[qg][tt][0]);
        float e1 = __builtin_amdgcn_exp2f(st[qg][tt][1]);
        float e2 = __builtin_amdgcn_exp2f(st[qg][tt][2]);
        float e3 = __builtin_amdgcn_exp2f(st[qg][tt][3]);
        pk[qg][tt][0] = rhu2(e0, e1);
        pk[qg][tt][1] = rhu2(e2, e3);
      }

    // PV: reads Vtb (visible since barrier B)
    __builtin_amdgcn_s_setprio(1);
#pragma unroll
    for (int c = 0; c < 2; c++) {
      bf16x8 bp[2];
#pragma unroll
      for (int qg = 0; qg < 2; qg++) {
        u32x4 bpr;
        bpr[0] = pk[qg][2 * c][0];
        bpr[1] = pk[qg][2 * c][1];
        bpr[2] = pk[qg][2 * c + 1][0];
        bpr[3] = pk[qg][2 * c + 1][1];
        bp[qg] = *(bf16x8*)&bpr;
      }
#pragma unroll
      for (int dt = 0; dt < 4; dt++) {
        bf16x8 av = *(const bf16x8*)&Vtb[(dt * 16 + fr) * 64 +
                                         ((c * 32 + fq * 8) ^ rx)];
        ot[0][dt] = __builtin_amdgcn_mfma_f32_16x16x32_bf16(av, bp[0], ot[0][dt], 0, 0, 0);
        ot[1][dt] = __builtin_amdgcn_mfma_f32_16x16x32_bf16(av, bp[1], ot[1][dt], 0, 0, 0);
      }
      osum[0] = __builtin_amdgcn_mfma_f32_16x16x32_bf16(onesf, bp[0], osum[0], 0, 0, 0);
      osum[1] = __builtin_amdgcn_mfma_f32_16x16x32_bf16(onesf, bp[1], osum[1], 0, 0, 0);
    }
    __builtin_amdgcn_s_setprio(0);

    cur = nxt;
  }

#pragma unroll
  for (int qg = 0; qg < 2; qg++) {
    float inv = 1.0f / osum[qg][0];
    size_t rowbase = base + (size_t)(q0 + qg * 64 + wave * 16 + fr) * E;
#pragma unroll
    for (int dt = 0; dt < 4; dt++) {
      uint32_t w0 = rhu2(ot[qg][dt][0] * inv, ot[qg][dt][1] * inv);
      uint32_t w1 = rhu2(ot[qg][dt][2] * inv, ot[qg][dt][3] * inv);
      *(uint32_t*)&o[rowbase + dt * 16 + fq * 4] = w0;
      *(uint32_t*)&o[rowbase + dt * 16 + fq * 4 + 2] = w1;
    }
  }
}

// ---------------------------------------------------------------------------
// ws: 3 x 1M (weights) + 3 x 8M (q/k/v) shorts = 54 MB.
// bf16 hidden_states lives in d_out's first 16 MB (dead before final GEMM).
// woT reuses wqT's slot (transposed only after the QKV GEMM has consumed
// wqT). Final GEMM writes fp32 to d_out.
// ---------------------------------------------------------------------------
extern "C" void kernel_launch(void* const* d_in, const int* in_sizes, int n_in,
                              void* d_out, int out_size, void* d_ws, size_t ws_size,
                              hipStream_t stream) {
  const float* hs = (const float*)d_in[0];
  const float* wq = (const float*)d_in[1];
  const float* wk = (const float*)d_in[2];
  const float* wv = (const float*)d_in[3];
  const float* wo = (const float*)d_in[4];
  unsigned short* ws = (unsigned short*)d_ws;

  unsigned short* wqT = ws;
  unsigned short* wkT = ws + 1048576;
  unsigned short* wvT = ws + 2097152;
  unsigned short* woT = wqT;
  unsigned short* qb  = ws + 3145728;
  unsigned short* kb  = qb + 8388608;
  unsigned short* vb  = kb + 8388608;
  unsigned short* ob  = qb;
  unsigned short* hsb = (unsigned short*)d_out;
  float* out = (float*)d_out;

  const int M = 8192, N = 1024, K = 1024;
  const float KSC = 0.125f * 1.44269504088896341f;  // head_scale * log2(e)

  cvt_f32_bf16<<<dim3(M * K / 4 / 256), 256, 0, stream>>>(hs, hsb, M * K / 4);

  dim3 tb(32, 8);
  transpose_w3<<<dim3(32, 32, 3), tb, 0, stream>>>(wq, wk, wv, wqT, wkT, wvT);

  gemm3<unsigned short><<<dim3(M / 128, N / 128, 3), 256, 0, stream>>>(
      hsb, wqT, wkT, wvT, qb, kb, vb, M, N, K, KSC);

  transpose_w<<<dim3(32, 32), tb, 0, stream>>>(wo, woT);

  attn_kernel<<<dim3(2048 / 128, 64), 256, 0, stream>>>(qb, kb, vb, ob);

  gemm3<float><<<dim3(M / 128, N / 128, 1), 256, 0, stream>>>(
      ob, woT, woT, woT, out, out, out, M, N, K, 1.0f);
}